// Round 9
// baseline (382.765 us; speedup 1.0000x reference)
//
#include <hip/hip_runtime.h>
#include <hip/hip_fp16.h>

#define NN 100000
#define NE 1600000
#define NHEADS 4
#define NEG_SLOPE 0.2f
#define NB ((NN + 255) / 256)
#define WINSZ 12500             // NN / 8 dst-window per XCD
#define CAP 48                  // bucket capacity per node (deg ~ Poisson(16))

typedef _Float16 f16x8 __attribute__((ext_vector_type(8)));
typedef float f32x4 __attribute__((ext_vector_type(4)));

// ---------------------------------------------------------------------------
// W[k][j] fp32 -> Wt[j][k] fp16 (transposed so B-fragments are contiguous in k)
__global__ __launch_bounds__(256) void convert_w_kernel(
    const float* __restrict__ W1, const float* __restrict__ W2,
    __half* __restrict__ W1t, __half* __restrict__ W2t)
{
    int i = blockIdx.x * 256 + threadIdx.x;       // 0..16383
    if (i >= 16384) return;
    int k = i >> 7, j = i & 127;
    W1t[j * 128 + k] = __float2half(W1[i]);
    W2t[j * 128 + k] = __float2half(W2[i]);
}

// ---------------------------------------------------------------------------
// MFMA GEMM + fused attention logits.
// h[row][j] = sum_k A[row][k] * W[k][j]; als/ald from fp32 accumulators.
// Block = 128 rows, 4 waves; wave handles two 16-row tiles sharing B-frags.
// mfma_f32_16x16x32_f16 layouts (m89-verified family):
//   A: row=l&15, k=8*(l>>4)+e   B: col=l&15, k=8*(l>>4)+e
//   D: col=l&15, row=4*(l>>4)+q    (so acc[n][q] = h[row0+lk*4+q][n*16+lr])
template <int AFP32>
__global__ __launch_bounds__(256) void gemm16_kernel(
    const void* __restrict__ Ap, const __half* __restrict__ Wt,
    const float* __restrict__ a_src, const float* __restrict__ a_dst,
    __half* __restrict__ h, float* __restrict__ als, float* __restrict__ ald)
{
    const int wave = threadIdx.x >> 6;
    const int l    = threadIdx.x & 63;
    const int lr   = l & 15;
    const int lk   = l >> 4;

    const int row0 = blockIdx.x * 128 + wave * 16;
    const int row1 = row0 + 64;
    const bool t1 = (row1 < NN);
    if (row0 >= NN) return;          // NN % 16 == 0: tiles all-or-nothing

    f16x8 a0[4], a1[4];
#pragma unroll
    for (int kk = 0; kk < 4; ++kk) {
        if (AFP32) {
            const float* xf = (const float*)Ap;
            const float4* p = reinterpret_cast<const float4*>(xf + (row0 + lr) * 128 + kk * 32 + lk * 8);
            float4 u = p[0], v = p[1];
            f16x8 a;
            a[0] = (_Float16)u.x; a[1] = (_Float16)u.y; a[2] = (_Float16)u.z; a[3] = (_Float16)u.w;
            a[4] = (_Float16)v.x; a[5] = (_Float16)v.y; a[6] = (_Float16)v.z; a[7] = (_Float16)v.w;
            a0[kk] = a;
        } else {
            const __half* xh = (const __half*)Ap;
            a0[kk] = *reinterpret_cast<const f16x8*>(xh + (row0 + lr) * 128 + kk * 32 + lk * 8);
        }
    }
    if (t1) {
#pragma unroll
        for (int kk = 0; kk < 4; ++kk) {
            if (AFP32) {
                const float* xf = (const float*)Ap;
                const float4* p = reinterpret_cast<const float4*>(xf + (row1 + lr) * 128 + kk * 32 + lk * 8);
                float4 u = p[0], v = p[1];
                f16x8 a;
                a[0] = (_Float16)u.x; a[1] = (_Float16)u.y; a[2] = (_Float16)u.z; a[3] = (_Float16)u.w;
                a[4] = (_Float16)v.x; a[5] = (_Float16)v.y; a[6] = (_Float16)v.z; a[7] = (_Float16)v.w;
                a1[kk] = a;
            } else {
                const __half* xh = (const __half*)Ap;
                a1[kk] = *reinterpret_cast<const f16x8*>(xh + (row1 + lr) * 128 + kk * 32 + lk * 8);
            }
        }
    }

    f32x4 acc0[8], acc1[8];
#pragma unroll
    for (int n = 0; n < 8; ++n) { acc0[n] = (f32x4)(0.f); acc1[n] = (f32x4)(0.f); }

#pragma unroll
    for (int n = 0; n < 8; ++n) {
#pragma unroll
        for (int kk = 0; kk < 4; ++kk) {
            f16x8 b = *reinterpret_cast<const f16x8*>(Wt + (n * 16 + lr) * 128 + kk * 32 + lk * 8);
            acc0[n] = __builtin_amdgcn_mfma_f32_16x16x32_f16(a0[kk], b, acc0[n], 0, 0, 0);
            if (t1)
                acc1[n] = __builtin_amdgcn_mfma_f32_16x16x32_f16(a1[kk], b, acc1[n], 0, 0, 0);
        }
    }

    // h store
#pragma unroll
    for (int n = 0; n < 8; ++n) {
#pragma unroll
        for (int q = 0; q < 4; ++q) {
            h[(row0 + lk * 4 + q) * 128 + n * 16 + lr] = __float2half(acc0[n][q]);
            if (t1)
                h[(row1 + lk * 4 + q) * 128 + n * 16 + lr] = __float2half(acc1[n][q]);
        }
    }

    // fused attention logits: als[row][hh] = sum_j h[row][j]*a_src[j] over head hh
    float asv[8], adv[8];
#pragma unroll
    for (int n = 0; n < 8; ++n) {
        asv[n] = a_src[n * 16 + lr];
        adv[n] = a_dst[n * 16 + lr];
    }
#pragma unroll
    for (int tile = 0; tile < 2; ++tile) {
        if (tile == 1 && !t1) break;
        const int rb = tile ? row1 : row0;
#pragma unroll
        for (int q = 0; q < 4; ++q) {
            float ps[4], pd[4];
#pragma unroll
            for (int hh = 0; hh < 4; ++hh) {
                float c0 = tile ? acc1[2 * hh][q]     : acc0[2 * hh][q];
                float c1 = tile ? acc1[2 * hh + 1][q] : acc0[2 * hh + 1][q];
                ps[hh] = c0 * asv[2 * hh] + c1 * asv[2 * hh + 1];
                pd[hh] = c0 * adv[2 * hh] + c1 * adv[2 * hh + 1];
            }
#pragma unroll
            for (int m = 1; m <= 8; m <<= 1) {
#pragma unroll
                for (int hh = 0; hh < 4; ++hh) {
                    ps[hh] += __shfl_xor(ps[hh], m, 64);
                    pd[hh] += __shfl_xor(pd[hh], m, 64);
                }
            }
            if (lr == 0) {
                int row = rb + lk * 4 + q;
                *reinterpret_cast<float4*>(als + row * 4) = make_float4(ps[0], ps[1], ps[2], ps[3]);
                *reinterpret_cast<float4*>(ald + row * 4) = make_float4(pd[0], pd[1], pd[2], pd[3]);
            }
        }
    }
}

// ---------------------------------------------------------------------------
// Single-pass bucket CSR, dst-windowed + XCD-affine (blockIdx&7 = window).
// x4 edges per thread: int4 dst load, 4 independent atomic->store chains (MLP).
__global__ void zero_deg_kernel(int* __restrict__ deg) {
    int i = blockIdx.x * blockDim.x + threadIdx.x;
    if (i < NN) deg[i] = 0;
}

__global__ void build_kernel(const int* __restrict__ ei, int* __restrict__ deg,
                             int* __restrict__ bucket)
{
    int w = blockIdx.x & 7;
    int base = (((blockIdx.x >> 3) * 256) + threadIdx.x) * 4;
    if (base >= NE) return;
    int4 d4 = *reinterpret_cast<const int4*>(ei + NE + base);
    int dd[4] = {d4.x, d4.y, d4.z, d4.w};
#pragma unroll
    for (int u = 0; u < 4; ++u) {
        int d = dd[u];
        if ((unsigned)(d - w * WINSZ) < (unsigned)WINSZ) {
            int s = ei[base + u];
            int pos = atomicAdd(&deg[d], 1);
            if (pos < CAP) bucket[d * CAP + pos] = s;   // overflow guard
        }
    }
}

// ---------------------------------------------------------------------------
// Gather-reduce: one wave per dst node, half2 per lane, x8 edge blocks.
// Cooperative weights WITHOUT barrier/LDS: in each x8 block, lane t computes
// weight(edge (t>>2)&7, head t&3) — one als gather + one exp per UNIQUE value
// (lanes 32-63 duplicate lanes 0-31) — then each lane pulls its 8 weights via
// ds_bpermute from lanes 4u+hd (<32). Wave-private; no lockstep coupling.
// mode 1: write relu(o) fp16 to yh (layer-1 mid). mode 0: write o fp32 to yf.
__global__ __launch_bounds__(256) void agg_kernel(
    const int* __restrict__ bucket, const int* __restrict__ deg,
    const float* __restrict__ als, const float* __restrict__ ald,
    const __half* __restrict__ h, const float* __restrict__ b,
    __half* __restrict__ yh, float* __restrict__ yf, int mode)
{
    const int wv = threadIdx.x >> 6;
    const int t  = threadIdx.x & 63;
    const int node = (blockIdx.x & 7) * WINSZ + (blockIdx.x >> 3) * 4 + wv;
    const int hd  = t >> 4;         // head this lane accumulates (channels 2t,2t+1)
    const int whd = t & 3;          // head this lane computes weights for
    const int hd4 = hd << 2;        // bpermute byte-addr base

    int cnt = deg[node]; if (cnt > CAP) cnt = CAP;
    const int* __restrict__ lst = bucket + node * CAP;
    const float aldw    = ald[node * 4 + whd];
    const float ald_own = ald[node * 4 + hd];

    const __half2* __restrict__ h2 = (const __half2*)h;
    float2 acc0 = make_float2(0.f, 0.f), acc1 = make_float2(0.f, 0.f);
    float den = 0.f;

    int k = 0;
    for (; k + 7 < cnt; k += 8) {
        // cooperative weight: one exp per unique (edge,head)
        int se = lst[k + ((t >> 2) & 7)];
        float v = als[se * 4 + whd] + aldw;
        v = v >= 0.f ? v : NEG_SLOPE * v;
        int wmei = __float_as_int(__expf(v));

        int s[8]; __half2 hv[8];
#pragma unroll
        for (int u = 0; u < 8; ++u) s[u] = lst[k + u];
#pragma unroll
        for (int u = 0; u < 8; ++u) hv[u] = h2[s[u] * 64 + t];
#pragma unroll
        for (int u = 0; u < 8; ++u) {
            float wu = __int_as_float(
                __builtin_amdgcn_ds_bpermute(u * 16 + hd4, wmei));
            float2 f = __half22float2(hv[u]);
            den += wu;
            if (u & 1) { acc1.x = fmaf(wu, f.x, acc1.x); acc1.y = fmaf(wu, f.y, acc1.y); }
            else       { acc0.x = fmaf(wu, f.x, acc0.x); acc0.y = fmaf(wu, f.y, acc0.y); }
        }
    }
    for (; k < cnt; ++k) {          // per-lane tail (<8 edges)
        int s = lst[k];
        float v = als[s * 4 + hd] + ald_own;
        v = v >= 0.f ? v : NEG_SLOPE * v;
        float w = __expf(v);
        float2 f = __half22float2(h2[s * 64 + t]);
        den += w;
        acc0.x = fmaf(w, f.x, acc0.x); acc0.y = fmaf(w, f.y, acc0.y);
    }

    float2 acc = make_float2(acc0.x + acc1.x, acc0.y + acc1.y);
    float inv = den > 0.f ? __frcp_rn(den) : 0.f;
    float2 bv = ((const float2*)b)[t];
    float ox = acc.x * inv + bv.x;
    float oy = acc.y * inv + bv.y;
    if (mode) {
        ((__half2*)yh)[node * 64 + t] = __floats2half2_rn(fmaxf(ox, 0.f), fmaxf(oy, 0.f));
    } else {
        ((float2*)yf)[node * 64 + t] = make_float2(ox, oy);
    }
}

// ---------------------------------------------------------------------------
extern "C" void kernel_launch(void* const* d_in, const int* in_sizes, int n_in,
                              void* d_out, int out_size, void* d_ws, size_t ws_size,
                              hipStream_t stream) {
    const float* x      = (const float*)d_in[0];
    const int*   ei     = (const int*)  d_in[1];
    const float* W1     = (const float*)d_in[2];
    const float* a_src1 = (const float*)d_in[3];
    const float* a_dst1 = (const float*)d_in[4];
    const float* b1     = (const float*)d_in[5];
    const float* W2     = (const float*)d_in[6];
    const float* a_src2 = (const float*)d_in[7];
    const float* a_dst2 = (const float*)d_in[8];
    const float* b2     = (const float*)d_in[9];

    char* ws = (char*)d_ws;
    __half* h       = (__half*)ws;                ws += sizeof(__half) * NN * 128;
    __half* y1h     = (__half*)ws;                ws += sizeof(__half) * NN * 128;
    __half* W1t     = (__half*)ws;                ws += sizeof(__half) * 128 * 128;
    __half* W2t     = (__half*)ws;                ws += sizeof(__half) * 128 * 128;
    float* als      = (float*)ws;                 ws += sizeof(float) * NN * 4;
    float* ald      = (float*)ws;                 ws += sizeof(float) * NN * 4;
    int*   deg      = (int*)ws;                   ws += sizeof(int) * NN;
    int*   bucket   = (int*)ws;                   ws += sizeof(int) * NN * CAP;
    float* out      = (float*)d_out;

    const int gemm_grid  = (NN + 127) / 128;
    const int build_grid = ((NE / 4 + 255) / 256) * 8;   // x8 windows, x4 edges/thread
    const int agg_grid   = 8 * (WINSZ / 4);              // window-major, XCD-affine

    // ---- CSR build (single pass, shared by both layers) + W conversion ----
    zero_deg_kernel<<<NB, 256, 0, stream>>>(deg);
    convert_w_kernel<<<64, 256, 0, stream>>>(W1, W2, W1t, W2t);
    build_kernel<<<build_grid, 256, 0, stream>>>(ei, deg, bucket);

    // ---- layer 1 (fp32 x converted in-register inside GEMM; logits fused) ----
    gemm16_kernel<1><<<gemm_grid, 256, 0, stream>>>(x, W1t, a_src1, a_dst1,
                                                    h, als, ald);
    agg_kernel<<<agg_grid, 256, 0, stream>>>(bucket, deg, als, ald, h, b1,
                                             y1h, nullptr, 1);

    // ---- layer 2 (ReLU already applied to y1h; logits fused) ----
    gemm16_kernel<0><<<gemm_grid, 256, 0, stream>>>(y1h, W2t, a_src2, a_dst2,
                                                    h, als, ald);
    agg_kernel<<<agg_grid, 256, 0, stream>>>(bucket, deg, als, ald, h, b2,
                                             nullptr, out, 0);
}

// Round 10
// 315.026 us; speedup vs baseline: 1.2150x; 1.2150x over previous
//
#include <hip/hip_runtime.h>
#include <hip/hip_fp16.h>

#define NN 100000
#define NE 1600000
#define NHEADS 4
#define NB ((NN + 255) / 256)
#define WINSZ 12500             // NN / 8 dst-window per XCD
#define CAP 48                  // bucket capacity per node (deg ~ Poisson(16))
#define INV_LN2 1.4426950408889634f

typedef _Float16 f16x8 __attribute__((ext_vector_type(8)));
typedef float f32x4 __attribute__((ext_vector_type(4)));

// ---------------------------------------------------------------------------
// W[k][j] fp32 -> Wt[j][k] fp16 (transposed so B-fragments are contiguous in k)
__global__ __launch_bounds__(256) void convert_w_kernel(
    const float* __restrict__ W1, const float* __restrict__ W2,
    __half* __restrict__ W1t, __half* __restrict__ W2t)
{
    int i = blockIdx.x * 256 + threadIdx.x;       // 0..16383
    if (i >= 16384) return;
    int k = i >> 7, j = i & 127;
    W1t[j * 128 + k] = __float2half(W1[i]);
    W2t[j * 128 + k] = __float2half(W2[i]);
}

// ---------------------------------------------------------------------------
// MFMA GEMM: h[row][j] = sum_k A[row][k] * W[k][j], all dims 128, fp32 acc.
// Block = 128 rows, 4 waves; wave handles two 16-row tiles sharing B-frags.
// A from global (fp32 converted in-register when AFP32); B from L1-resident Wt.
// mfma_f32_16x16x32_f16 layouts (m89-verified family):
//   A: row=l&15, k=8*(l>>4)+e   B: col=l&15, k=8*(l>>4)+e
//   D: col=l&15, row=4*(l>>4)+q
template <int AFP32>
__global__ __launch_bounds__(256) void gemm16_kernel(
    const void* __restrict__ Ap, const __half* __restrict__ Wt,
    __half* __restrict__ h)
{
    const int wave = threadIdx.x >> 6;
    const int l    = threadIdx.x & 63;
    const int lr   = l & 15;
    const int lk   = l >> 4;

    const int row0 = blockIdx.x * 128 + wave * 16;
    const int row1 = row0 + 64;
    const bool t1 = (row1 < NN);
    if (row0 >= NN) return;          // NN % 16 == 0: tiles all-or-nothing

    f16x8 a0[4], a1[4];
#pragma unroll
    for (int kk = 0; kk < 4; ++kk) {
        if (AFP32) {
            const float* xf = (const float*)Ap;
            const float4* p = reinterpret_cast<const float4*>(xf + (row0 + lr) * 128 + kk * 32 + lk * 8);
            float4 u = p[0], v = p[1];
            f16x8 a;
            a[0] = (_Float16)u.x; a[1] = (_Float16)u.y; a[2] = (_Float16)u.z; a[3] = (_Float16)u.w;
            a[4] = (_Float16)v.x; a[5] = (_Float16)v.y; a[6] = (_Float16)v.z; a[7] = (_Float16)v.w;
            a0[kk] = a;
        } else {
            const __half* xh = (const __half*)Ap;
            a0[kk] = *reinterpret_cast<const f16x8*>(xh + (row0 + lr) * 128 + kk * 32 + lk * 8);
        }
    }
    if (t1) {
#pragma unroll
        for (int kk = 0; kk < 4; ++kk) {
            if (AFP32) {
                const float* xf = (const float*)Ap;
                const float4* p = reinterpret_cast<const float4*>(xf + (row1 + lr) * 128 + kk * 32 + lk * 8);
                float4 u = p[0], v = p[1];
                f16x8 a;
                a[0] = (_Float16)u.x; a[1] = (_Float16)u.y; a[2] = (_Float16)u.z; a[3] = (_Float16)u.w;
                a[4] = (_Float16)v.x; a[5] = (_Float16)v.y; a[6] = (_Float16)v.z; a[7] = (_Float16)v.w;
                a1[kk] = a;
            } else {
                const __half* xh = (const __half*)Ap;
                a1[kk] = *reinterpret_cast<const f16x8*>(xh + (row1 + lr) * 128 + kk * 32 + lk * 8);
            }
        }
    }

    f32x4 acc0[8], acc1[8];
#pragma unroll
    for (int n = 0; n < 8; ++n) { acc0[n] = (f32x4)(0.f); acc1[n] = (f32x4)(0.f); }

#pragma unroll
    for (int n = 0; n < 8; ++n) {
#pragma unroll
        for (int kk = 0; kk < 4; ++kk) {
            f16x8 b = *reinterpret_cast<const f16x8*>(Wt + (n * 16 + lr) * 128 + kk * 32 + lk * 8);
            acc0[n] = __builtin_amdgcn_mfma_f32_16x16x32_f16(a0[kk], b, acc0[n], 0, 0, 0);
            if (t1)
                acc1[n] = __builtin_amdgcn_mfma_f32_16x16x32_f16(a1[kk], b, acc1[n], 0, 0, 0);
        }
    }

#pragma unroll
    for (int n = 0; n < 8; ++n) {
#pragma unroll
        for (int q = 0; q < 4; ++q) {
            h[(row0 + lk * 4 + q) * 128 + n * 16 + lr] = __float2half(acc0[n][q]);
            if (t1)
                h[(row1 + lk * 4 + q) * 128 + n * 16 + lr] = __float2half(acc1[n][q]);
        }
    }
}

// ---------------------------------------------------------------------------
// Attention logits, PRE-SCALED by 1/ln2 so agg can use exp2 directly:
//   als[row][hd] = (1/ln2) * sum_c h[row][hd*32+c]*a_src[hd*32+c]
// (leaky_relu commutes with positive scaling, so exp(leaky(x)) == exp2(leaky(x/ln2)))
__global__ __launch_bounds__(256) void al_kernel(
    const __half* __restrict__ h, const float* __restrict__ a_src,
    const float* __restrict__ a_dst, float* __restrict__ als,
    float* __restrict__ ald)
{
    int idx = blockIdx.x * 256 + threadIdx.x;     // (row, head)
    if (idx >= NN * 4) return;
    int row = idx >> 2, hd = idx & 3;
    const __half2* hp = reinterpret_cast<const __half2*>(h + row * 128 + hd * 32);
    const float* asv = a_src + hd * 32;
    const float* adv = a_dst + hd * 32;
    float ps = 0.f, pd = 0.f;
#pragma unroll
    for (int c2 = 0; c2 < 16; ++c2) {
        float2 f = __half22float2(hp[c2]);
        ps = fmaf(f.x, asv[2 * c2], ps); ps = fmaf(f.y, asv[2 * c2 + 1], ps);
        pd = fmaf(f.x, adv[2 * c2], pd); pd = fmaf(f.y, adv[2 * c2 + 1], pd);
    }
    als[idx] = ps * INV_LN2;
    ald[idx] = pd * INV_LN2;
}

// ---------------------------------------------------------------------------
// Single-pass bucket CSR, dst-windowed + XCD-affine (blockIdx&7 = window).
// x4 edges per thread: int4 dst load, 4 independent atomic->store chains (MLP).
__global__ void zero_deg_kernel(int* __restrict__ deg) {
    int i = blockIdx.x * blockDim.x + threadIdx.x;
    if (i < NN) deg[i] = 0;
}

__global__ void build_kernel(const int* __restrict__ ei, int* __restrict__ deg,
                             int* __restrict__ bucket)
{
    int w = blockIdx.x & 7;
    int base = (((blockIdx.x >> 3) * 256) + threadIdx.x) * 4;
    if (base >= NE) return;
    int4 d4 = *reinterpret_cast<const int4*>(ei + NE + base);
    int dd[4] = {d4.x, d4.y, d4.z, d4.w};
#pragma unroll
    for (int u = 0; u < 4; ++u) {
        int d = dd[u];
        if ((unsigned)(d - w * WINSZ) < (unsigned)WINSZ) {
            int s = ei[base + u];
            int pos = atomicAdd(&deg[d], 1);
            if (pos < CAP) bucket[d * CAP + pos] = s;   // overflow guard
        }
    }
}

// ---------------------------------------------------------------------------
// Gather-reduce: one wave per dst node, half2 per lane, fully-predicated x8
// edge blocks (no scalar tail — OOB lanes clamp index, weight forced to 0, so
// the tail keeps the full 8-deep gather MLP). Per-lane weights (redundant
// across the 16 lanes of a head but INDEPENDENT — r8/r9 showed cooperative
// schemes serialize the critical path and lose).
// mode 1: write relu(o) fp16 to yh (layer-1 mid). mode 0: write o fp32 to yf.
__global__ __launch_bounds__(256) void agg_kernel(
    const int* __restrict__ bucket, const int* __restrict__ deg,
    const float* __restrict__ als, const float* __restrict__ ald,
    const __half* __restrict__ h, const float* __restrict__ b,
    __half* __restrict__ yh, float* __restrict__ yf, int mode)
{
    const int wv = threadIdx.x >> 6;
    const int t  = threadIdx.x & 63;
    const int node = (blockIdx.x & 7) * WINSZ + (blockIdx.x >> 3) * 4 + wv;
    const int hd  = t >> 4;         // head for channels 2t, 2t+1

    int cnt = deg[node]; if (cnt > CAP) cnt = CAP;
    const int* __restrict__ lst = bucket + node * CAP;
    const float ad = ald[node * 4 + hd];

    const __half2* __restrict__ h2 = (const __half2*)h;
    float2 acc0 = make_float2(0.f, 0.f), acc1 = make_float2(0.f, 0.f);
    float den = 0.f;
    const int lim = cnt - 1;

    for (int k = 0; k < cnt; k += 8) {
        int s[8]; float w[8]; __half2 hv[8];
#pragma unroll
        for (int u = 0; u < 8; ++u) {
            int idx = k + u;
            s[u] = lst[idx < lim ? idx : lim];     // clamped (OOB reuses last)
        }
#pragma unroll
        for (int u = 0; u < 8; ++u) {
            float v = als[s[u] * 4 + hd] + ad;     // pre-scaled by 1/ln2
            v = fmaxf(v, 0.2f * v);                // leaky (branch-free)
            w[u] = __builtin_amdgcn_exp2f(v);
            hv[u] = h2[s[u] * 64 + t];
        }
#pragma unroll
        for (int u = 0; u < 8; ++u) {
            float wu = (k + u < cnt) ? w[u] : 0.f; // predicate tail
            float2 f = __half22float2(hv[u]);
            den += wu;
            if (u & 1) { acc1.x = fmaf(wu, f.x, acc1.x); acc1.y = fmaf(wu, f.y, acc1.y); }
            else       { acc0.x = fmaf(wu, f.x, acc0.x); acc0.y = fmaf(wu, f.y, acc0.y); }
        }
    }

    float2 acc = make_float2(acc0.x + acc1.x, acc0.y + acc1.y);
    float inv = den > 0.f ? __frcp_rn(den) : 0.f;
    float2 bv = ((const float2*)b)[t];
    float ox = acc.x * inv + bv.x;
    float oy = acc.y * inv + bv.y;
    if (mode) {
        ((__half2*)yh)[node * 64 + t] = __floats2half2_rn(fmaxf(ox, 0.f), fmaxf(oy, 0.f));
    } else {
        ((float2*)yf)[node * 64 + t] = make_float2(ox, oy);
    }
}

// ---------------------------------------------------------------------------
extern "C" void kernel_launch(void* const* d_in, const int* in_sizes, int n_in,
                              void* d_out, int out_size, void* d_ws, size_t ws_size,
                              hipStream_t stream) {
    const float* x      = (const float*)d_in[0];
    const int*   ei     = (const int*)  d_in[1];
    const float* W1     = (const float*)d_in[2];
    const float* a_src1 = (const float*)d_in[3];
    const float* a_dst1 = (const float*)d_in[4];
    const float* b1     = (const float*)d_in[5];
    const float* W2     = (const float*)d_in[6];
    const float* a_src2 = (const float*)d_in[7];
    const float* a_dst2 = (const float*)d_in[8];
    const float* b2     = (const float*)d_in[9];

    char* ws = (char*)d_ws;
    __half* h       = (__half*)ws;                ws += sizeof(__half) * NN * 128;
    __half* y1h     = (__half*)ws;                ws += sizeof(__half) * NN * 128;
    __half* W1t     = (__half*)ws;                ws += sizeof(__half) * 128 * 128;
    __half* W2t     = (__half*)ws;                ws += sizeof(__half) * 128 * 128;
    float* als      = (float*)ws;                 ws += sizeof(float) * NN * 4;
    float* ald      = (float*)ws;                 ws += sizeof(float) * NN * 4;
    int*   deg      = (int*)ws;                   ws += sizeof(int) * NN;
    int*   bucket   = (int*)ws;                   ws += sizeof(int) * NN * CAP;
    float* out      = (float*)d_out;

    const int gemm_grid  = (NN + 127) / 128;
    const int build_grid = ((NE / 4 + 255) / 256) * 8;   // x8 windows, x4 edges/thread
    const int agg_grid   = 8 * (WINSZ / 4);              // window-major, XCD-affine
    const int al_grid    = (NN * 4 + 255) / 256;

    // ---- CSR build (single pass, shared by both layers) + W conversion ----
    zero_deg_kernel<<<NB, 256, 0, stream>>>(deg);
    convert_w_kernel<<<64, 256, 0, stream>>>(W1, W2, W1t, W2t);
    build_kernel<<<build_grid, 256, 0, stream>>>(ei, deg, bucket);

    // ---- layer 1 (fp32 x converted in-register inside GEMM) ----
    gemm16_kernel<1><<<gemm_grid, 256, 0, stream>>>(x, W1t, h);
    al_kernel<<<al_grid, 256, 0, stream>>>(h, a_src1, a_dst1, als, ald);
    agg_kernel<<<agg_grid, 256, 0, stream>>>(bucket, deg, als, ald, h, b1,
                                             y1h, nullptr, 1);

    // ---- layer 2 (ReLU already applied to y1h) ----
    gemm16_kernel<0><<<gemm_grid, 256, 0, stream>>>(y1h, W2t, h);
    al_kernel<<<al_grid, 256, 0, stream>>>(h, a_src2, a_dst2, als, ald);
    agg_kernel<<<agg_grid, 256, 0, stream>>>(bucket, deg, als, ald, h, b2,
                                             nullptr, out, 0);
}